// Round 17
// baseline (180.211 us; speedup 1.0000x reference)
//
#include <hip/hip_runtime.h>
#include <math.h>

// Problem constants
#define B_  4
#define N_  170
#define T_  96
#define D_  256
#define H_  8
#define HD_ 32
#define R_  (B_*N_*T_)    // 65280 rows
#define BN_ (B_*N_)       // 680 bn values; grid = 1360 (bn, half)
#define WSZ (D_*D_)       // 65536 per weight matrix

typedef short  bf16x8 __attribute__((ext_vector_type(8)));
typedef float  f32x4  __attribute__((ext_vector_type(4)));
typedef unsigned int u32;

// ---- mega_lite LDS (72 KB -> 2 blocks/CU). 256B sub-planes as proven ----
//   XB: X k-half planes [ksl 0..3][rt 0..5][kg 0..3] -> later P scratch
//   KB: K planes for 4 local heads [hl][rt][kg]
//   VB: q planes (K-style) -> V planes [hl][s2][n2][kg]
#define XB   0
#define KB   24576
#define VB   49152
#define LDSZ 73728

__device__ __forceinline__ ushort to_bf16(float x)
{
    uint u = __builtin_bit_cast(uint, x);
    u += 0x8000u;                      // round-half-up
    return (ushort)(u >> 16);
}

__device__ __forceinline__ uint pack2(float x0, float x1)
{
    return (uint)to_bf16(x0) | ((uint)to_bf16(x1) << 16);
}

__device__ __forceinline__ uint4 pack8(float4 a0, float4 a1)
{
    uint4 r;
    r.x = pack2(a0.x, a0.y); r.y = pack2(a0.z, a0.w);
    r.z = pack2(a1.x, a1.y); r.w = pack2(a1.z, a1.w);
    return r;
}

#define MFMA(a, b, c) __builtin_amdgcn_mfma_f32_16x16x32_bf16((a), (b), (c), 0, 0, 0)

// async global->LDS, 16B/lane (wo_kernel staging)
__device__ __forceinline__ void async_load16(const void* g, void* l)
{
    __builtin_amdgcn_global_load_lds(
        (const u32 __attribute__((address_space(1)))*)g,
        (u32 __attribute__((address_space(3)))*)l,
        16, 0, 0);
}

// ---------------------------------------------------------------------------
// Kernel 0: W prep. W[col][k] fp32 -> single ROUNDED bf16, chunked layout
// [k/8][col][8] per matrix. Wq gets 1/sqrt(32) folded in. 0=Wq 1=Wk 2=Wv 3=Wo.
// ---------------------------------------------------------------------------
__global__ __launch_bounds__(256)
void splitw_kernel(const float* __restrict__ Wq, const float* __restrict__ Wk,
                   const float* __restrict__ Wv, const float* __restrict__ Wo,
                   ushort* __restrict__ whi)
{
    const int gid = blockIdx.x * 256 + threadIdx.x;   // 32768 chunks
    const int mat = gid >> 13;
    const int rem = gid & 8191;
    const int col = rem >> 5;
    const int kc  = rem & 31;
    const float* W = (mat == 0) ? Wq : (mat == 1) ? Wk : (mat == 2) ? Wv : Wo;
    const float s  = (mat == 0) ? 0.17677669529663687f : 1.0f;
    const float* p = W + (size_t)col * D_ + kc * 8;
    float4 a0 = *(const float4*)p;
    float4 a1 = *(const float4*)(p + 4);
    a0.x *= s; a0.y *= s; a0.z *= s; a0.w *= s;
    a1.x *= s; a1.y *= s; a1.z *= s; a1.w *= s;
    const size_t off = (size_t)mat * WSZ + ((size_t)kc * 256 + col) * 8;
    *(uint4*)(whi + off) = pack8(a0, a1);
}

// ---------------------------------------------------------------------------
// mega_lite: one block per (bn, head-half). 512 threads = 8 waves; LDS 72 KB
// -> 2 blocks/CU (cross-block latency hiding). X staged in k-halves into XB
// (GEMMs accumulate over 2 substeps); pf-register prefetch issued during the
// preceding GEMM so staging phases are ds_write-only. Wave wv owns d-tile wv
// (16 cols at hb*128 + wv*16) in all GEMMs; attention: head hl = wv>>1,
// row-half wv&1 (R9-verbatim body). O -> global bf16 for wo_kernel.
// ---------------------------------------------------------------------------
__global__ __launch_bounds__(512)
void mega_kernel(const float* __restrict__ Xq, const float* __restrict__ Xk,
                 const float* __restrict__ Xv, const ushort* __restrict__ W,
                 const float* __restrict__ bq, const float* __restrict__ bk,
                 const float* __restrict__ bv, ushort* __restrict__ obuf)
{
    __shared__ __align__(16) char lds[LDSZ];

    const int bx   = blockIdx.x;
    const int bn   = bx >> 1;
    const int hb   = bx & 1;         // head-half: heads hb*4..hb*4+3
    const int tid  = threadIdx.x;
    const int wv   = tid >> 6;       // 0..7
    const int lane = tid & 63;
    const int lr   = lane & 15;
    const int kgl  = lane >> 4;
    const int hl   = wv >> 1;        // local head 0..3
    const int ib   = (wv & 1) * 3;   // attention irow base
    const int dc0  = hb * 128;       // global d-col base
    const size_t xoff = (size_t)bn * T_ * D_;

    // staging coords: 1536 chunks (96 rows x 16 kc) over 512 thr = 3/thread
    int srow[3], skc[3]; uint saddr[3];
    #pragma unroll
    for (int c = 0; c < 3; c++) {
        const int cc = tid + c * 512;
        const int row = cc % 96, kc = cc / 96;    // kc 0..15
        srow[c] = row; skc[c] = kc;
        saddr[c] = (uint)(((((kc >> 2) * 6 + (row >> 4)) * 4 + (kc & 3)) * 256)
                          + (row & 15) * 16);
    }

    float4 pf[6];
#define PFETCH(X, kh) do { \
        _Pragma("unroll") \
        for (int c = 0; c < 3; c++) { \
            const float* p_ = (X) + xoff + srow[c] * D_ + (kh) * 128 + skc[c] * 8; \
            pf[2*c] = *(const float4*)p_; pf[2*c+1] = *(const float4*)(p_ + 4); \
        } \
    } while (0)
#define STW() do { \
        _Pragma("unroll") \
        for (int c = 0; c < 3; c++) \
            *(uint4*)(lds + XB + saddr[c]) = pack8(pf[2*c], pf[2*c+1]); \
    } while (0)
// GEMM substep, output (d, t): ACC[nt] += Wfrag x Xfrag, 4 ksl x 6 nt
#define GEMM_WN(Wbase, kh, ACC) do { \
        _Pragma("unroll") \
        for (int ksl = 0; ksl < 4; ksl++) { \
            bf16x8 wf = *(const bf16x8*)((Wbase) + \
                ((size_t)((kh)*16 + ksl*4 + kgl)*256 + dc0 + wv*16 + lr)*8); \
            _Pragma("unroll") \
            for (int nt = 0; nt < 6; nt++) { \
                bf16x8 xb = *(const bf16x8*)(lds + XB + ((ksl*6+nt)*4+kgl)*256 + lr*16); \
                ACC[nt] = MFMA(wf, xb, ACC[nt]); \
            } \
        } \
    } while (0)
// GEMM substep, output (t, d): ACC[mt] += Xfrag x Wfrag
#define GEMM_NW(Wbase, kh, ACC) do { \
        _Pragma("unroll") \
        for (int ksl = 0; ksl < 4; ksl++) { \
            bf16x8 wf = *(const bf16x8*)((Wbase) + \
                ((size_t)((kh)*16 + ksl*4 + kgl)*256 + dc0 + wv*16 + lr)*8); \
            _Pragma("unroll") \
            for (int mt = 0; mt < 6; mt++) { \
                bf16x8 xa = *(const bf16x8*)(lds + XB + ((ksl*6+mt)*4+kgl)*256 + lr*16); \
                ACC[mt] = MFMA(xa, wf, ACC[mt]); \
            } \
        } \
    } while (0)

    // ---- P0: stage XqA; pf XqB ----
    PFETCH(Xq, 0); STW();
    PFETCH(Xq, 1);
    __syncthreads();                               // (0)

    // ---- P1: q-GEMM substep A ----
    f32x4 qacc[6];
    #pragma unroll
    for (int nt = 0; nt < 6; nt++) qacc[nt] = (f32x4)0.f;
    GEMM_WN(W, 0, qacc);
    __syncthreads();                               // (1)

    // ---- P2: write XqB; pf XkA ----
    STW(); PFETCH(Xk, 0);
    __syncthreads();                               // (2)

    // ---- P3: q-GEMM substep B + q-epi -> VB (q planes, K-style, hl) ----
    GEMM_WN(W, 1, qacc);
    {
        const float qs = 0.17677669529663687f;
        const int kg = (wv & 1)*2 + (kgl >> 1);
        float4 b4 = *(const float4*)(bq + dc0 + wv*16 + kgl*4);
        #pragma unroll
        for (int nt = 0; nt < 6; nt++) {
            ushort4 o;
            o.x = to_bf16(qacc[nt][0] + b4.x*qs);
            o.y = to_bf16(qacc[nt][1] + b4.y*qs);
            o.z = to_bf16(qacc[nt][2] + b4.z*qs);
            o.w = to_bf16(qacc[nt][3] + b4.w*qs);
            *(ushort4*)(lds + VB + ((hl*6+nt)*4+kg)*256 + lr*16 + (kgl&1)*8) = o;
        }
    }
    __syncthreads();                               // (3)

    // ---- P4: write XkA; pf XkB ----
    STW(); PFETCH(Xk, 1);
    __syncthreads();                               // (4)

    // ---- P5: k-GEMM substep A; qf pull (q planes, before V overwrite) ----
    f32x4 kacc[6];
    #pragma unroll
    for (int nt = 0; nt < 6; nt++) kacc[nt] = (f32x4)0.f;
    GEMM_WN(W + WSZ, 0, kacc);
    bf16x8 qf[3];
    #pragma unroll
    for (int j = 0; j < 3; j++)
        qf[j] = *(const bf16x8*)(lds + VB + ((hl*6 + ib + j)*4 + kgl)*256 + lr*16);
    __syncthreads();                               // (5)

    // ---- P6: write XkB; pf XvA ----
    STW(); PFETCH(Xv, 0);
    __syncthreads();                               // (6)

    // ---- P7: k-GEMM substep B + k-epi -> KB ----
    GEMM_WN(W + WSZ, 1, kacc);
    {
        const int kg = (wv & 1)*2 + (kgl >> 1);
        float4 b4 = *(const float4*)(bk + dc0 + wv*16 + kgl*4);
        #pragma unroll
        for (int nt = 0; nt < 6; nt++) {
            ushort4 o;
            o.x = to_bf16(kacc[nt][0] + b4.x);
            o.y = to_bf16(kacc[nt][1] + b4.y);
            o.z = to_bf16(kacc[nt][2] + b4.z);
            o.w = to_bf16(kacc[nt][3] + b4.w);
            *(ushort4*)(lds + KB + ((hl*6+nt)*4+kg)*256 + lr*16 + (kgl&1)*8) = o;
        }
    }
    __syncthreads();                               // (7)

    // ---- P8: write XvA; pf XvB ----
    STW(); PFETCH(Xv, 1);
    __syncthreads();                               // (8)

    // ---- P9: v-GEMM substep A ----
    f32x4 vacc[6];
    #pragma unroll
    for (int mt = 0; mt < 6; mt++) vacc[mt] = (f32x4)0.f;
    GEMM_NW(W + 2*WSZ, 0, vacc);
    __syncthreads();                               // (9)

    // ---- P10: write XvB ----
    STW();
    __syncthreads();                               // (10)

    // ---- P11: v-GEMM substep B + v-epi -> VB (q dead since P5 pull) ----
    GEMM_NW(W + 2*WSZ, 1, vacc);
    {
        const int n2v = wv & 1;
        const float bvv = bv[dc0 + wv*16 + lr];
        #pragma unroll
        for (int mt = 0; mt < 6; mt++) {
            const int kvkg = mt*2 + (kgl >> 1);
            const int s2 = kvkg >> 2, kgv = kvkg & 3;
            ushort4 o;
            o.x = to_bf16(vacc[mt][0] + bvv);
            o.y = to_bf16(vacc[mt][1] + bvv);
            o.z = to_bf16(vacc[mt][2] + bvv);
            o.w = to_bf16(vacc[mt][3] + bvv);
            *(ushort4*)(lds + VB + (((hl*3+s2)*2+n2v)*4+kgv)*256 + lr*16 + (kgl&1)*8) = o;
        }
    }
    __syncthreads();                               // (11)

    // ---- P12: attention (R9-verbatim, head hl); P scratch in XB (X dead) ----
    f32x4 oacc[3][2];
    #pragma unroll
    for (int j = 0; j < 3; j++) { oacc[j][0] = (f32x4)0.f; oacc[j][1] = (f32x4)0.f; }
    {
        char* sw = lds + XB + wv * 3072;           // 12 planes x 256B
        #pragma unroll
        for (int j = 0; j < 3; j++) {
            f32x4 s[6];
            #pragma unroll
            for (int mt = 0; mt < 6; mt++) {
                bf16x8 kf = *(const bf16x8*)(lds + KB + ((hl*6+mt)*4+kgl)*256 + lr*16);
                s[mt] = MFMA(kf, qf[j], (f32x4)0.f);   // rows kv, col q = lr
            }
            float mx = s[0][0];
            #pragma unroll
            for (int mt = 0; mt < 6; mt++)
                #pragma unroll
                for (int r = 0; r < 4; r++) mx = fmaxf(mx, s[mt][r]);
            mx = fmaxf(mx, __shfl_xor(mx, 16));
            mx = fmaxf(mx, __shfl_xor(mx, 32));
            float sum = 0.f;
            #pragma unroll
            for (int mt = 0; mt < 6; mt++)
                #pragma unroll
                for (int r = 0; r < 4; r++) {
                    float e = __expf(s[mt][r] - mx);
                    s[mt][r] = e; sum += e;
                }
            sum += __shfl_xor(sum, 16);
            sum += __shfl_xor(sum, 32);
            const float inv = 1.f / sum;
            #pragma unroll
            for (int mt = 0; mt < 6; mt++) {
                uint2 u2;
                u2.x = pack2(s[mt][0]*inv, s[mt][1]*inv);
                u2.y = pack2(s[mt][2]*inv, s[mt][3]*inv);
                *(uint2*)(sw + (mt*2 + (kgl>>1))*256 + lr*16 + (kgl&1)*8) = u2;
            }
            #pragma unroll
            for (int s2 = 0; s2 < 3; s2++) {
                bf16x8 pa = *(const bf16x8*)(sw + (s2*4+kgl)*256 + lr*16);
                #pragma unroll
                for (int n2 = 0; n2 < 2; n2++) {
                    bf16x8 vf = *(const bf16x8*)(lds + VB + (((hl*3+s2)*2+n2)*4+kgl)*256 + lr*16);
                    oacc[j][n2] = MFMA(pa, vf, oacc[j][n2]);
                }
            }
        }
    }

    // ---- O -> global bf16 row-major [bn*96+t][256] ----
    #pragma unroll
    for (int j = 0; j < 3; j++)
        #pragma unroll
        for (int n2 = 0; n2 < 2; n2++) {
            const int col = dc0 + hl*32 + n2*16 + lr;
            #pragma unroll
            for (int r = 0; r < 4; r++) {
                const int t = (ib + j)*16 + kgl*4 + r;
                obuf[((size_t)(bn*T_ + t))*D_ + col] = to_bf16(oacc[j][n2][r]);
            }
        }
#undef PFETCH
#undef STW
#undef GEMM_WN
#undef GEMM_NW
}

// ---------------------------------------------------------------------------
// wo_kernel (R6-verified structure, single-bf16 W): out = O @ Wo^T + bo.
// BM=128, BN=128, BK=32, 256 thr = 4 waves (2x2, 64x64/wave); A (O bf16) and
// B (Wo bf16) via global_load_lds double buffer; ~33 KB LDS -> multi-block/CU.
// ---------------------------------------------------------------------------
__global__ __launch_bounds__(256)
void wo_kernel(const ushort* __restrict__ Obf, const ushort* __restrict__ whi,
               const float* __restrict__ bo, float* __restrict__ io)
{
    const int tid  = threadIdx.x;
    const int lane = tid & 63;
    const int w    = tid >> 6;
    const int col0 = blockIdx.x * 128;
    const int row0 = blockIdx.y * 128;
    const int wr   = w >> 1;
    const int wc   = w & 1;
    const int lr   = lane & 15;
    const int kgl  = lane >> 4;
    const ushort* Wh = whi + (size_t)3 * WSZ;

    __shared__ __align__(16) char Alds[2][8320];   // 4 planes x 130 chunks
    __shared__ __align__(16) char Blds[2][8320];

    // A: 2 gl_lds issues/wave (s = w*2+i: kg = s>>1, rhalf = s&1)
    const ushort* pa[2];
    uint wa[2];
    #pragma unroll
    for (int i = 0; i < 2; i++) {
        const int s = w * 2 + i, kg = s >> 1, rhalf = s & 1;
        pa[i] = Obf + (size_t)(row0 + rhalf * 64 + lane) * D_ + kg * 8;
        wa[i] = (uint)__builtin_amdgcn_readfirstlane((kg * 130 + rhalf * 64) * 16);
    }
    // B: 2 gl_lds issues/wave
    const ushort* pb[2];
    uint wb[2];
    #pragma unroll
    for (int i = 0; i < 2; i++) {
        const int s = w * 2 + i, kg = s >> 1, colh = s & 1;
        pb[i] = Wh + ((size_t)kg * 256 + col0 + colh * 64 + lane) * 8;
        wb[i] = (uint)__builtin_amdgcn_readfirstlane((kg * 130 + colh * 64) * 16);
    }

    f32x4 acc[4][4];
    #pragma unroll
    for (int m = 0; m < 4; m++)
        #pragma unroll
        for (int n = 0; n < 4; n++) acc[m][n] = (f32x4)0.f;

    // prologue
    #pragma unroll
    for (int i = 0; i < 2; i++) async_load16(pa[i], Alds[0] + wa[i]);
    #pragma unroll
    for (int i = 0; i < 2; i++) async_load16(pb[i], Blds[0] + wb[i]);
    __syncthreads();

    for (int t = 0; t < 8; t++) {
        const int cur = t & 1, nxt = cur ^ 1;
        if (t < 7) {
            #pragma unroll
            for (int i = 0; i < 2; i++)
                async_load16(pa[i] + (size_t)(t + 1) * 32, Alds[nxt] + wa[i]);
            #pragma unroll
            for (int i = 0; i < 2; i++)
                async_load16(pb[i] + (size_t)(t + 1) * 8192, Blds[nxt] + wb[i]);
        }
        bf16x8 a[4];
        #pragma unroll
        for (int m = 0; m < 4; m++)
            a[m] = *(const bf16x8*)(Alds[cur] + (kgl*130 + wr*64 + m*16 + lr) * 16);
        #pragma unroll
        for (int n = 0; n < 4; n++) {
            const int cb = wc*64 + n*16 + lr;
            bf16x8 bh = *(const bf16x8*)(Blds[cur] + (kgl*130 + cb) * 16);
            #pragma unroll
            for (int m = 0; m < 4; m++)
                acc[m][n] = MFMA(a[m], bh, acc[m][n]);
        }
        __syncthreads();
    }

    #pragma unroll
    for (int n = 0; n < 4; n++) {
        const int gcol = col0 + wc*64 + n*16 + lr;
        const float bv = bo[gcol];
        #pragma unroll
        for (int m = 0; m < 4; m++) {
            #pragma unroll
            for (int reg = 0; reg < 4; reg++) {
                const int grow = row0 + wr*64 + m*16 + kgl*4 + reg;
                io[(size_t)grow * D_ + gcol] = acc[m][n][reg] + bv;
            }
        }
    }
}

// ---------------------------------------------------------------------------
extern "C" void kernel_launch(void* const* d_in, const int* in_sizes, int n_in,
                              void* d_out, int out_size, void* d_ws, size_t ws_size,
                              hipStream_t stream)
{
    const float* query = (const float*)d_in[0];
    const float* key   = (const float*)d_in[1];
    const float* value = (const float*)d_in[2];
    // d_in[3..5]: pattern_matrix, Wp, bp -- mathematically a no-op (mask == 1)
    const float* Wq = (const float*)d_in[6];
    const float* bq = (const float*)d_in[7];
    const float* Wk = (const float*)d_in[8];
    const float* bk = (const float*)d_in[9];
    const float* Wv = (const float*)d_in[10];
    const float* bv = (const float*)d_in[11];
    const float* Wo = (const float*)d_in[12];
    const float* bo = (const float*)d_in[13];

    float*  out  = (float*)d_out;
    ushort* whi  = (ushort*)d_ws;                      // 512 KB
    ushort* obuf = whi + (size_t)4 * WSZ;              // attn out bf16, 33 MB

    splitw_kernel<<<dim3(128), 256, 0, stream>>>(Wq, Wk, Wv, Wo, whi);
    mega_kernel<<<dim3(BN_ * 2), 512, 0, stream>>>(
        query, key, value, whi, bq, bk, bv, obuf);
    wo_kernel<<<dim3(2, R_ / 128), 256, 0, stream>>>(obuf, whi, bo, out);
}